// Round 21
// baseline (53.275 us; speedup 1.0000x reference)
//
#include <hip/hip_runtime.h>
#include <math.h>

#define BB 2
#define CC 256
#define GG 8
#define DD 32
#define HH 48
#define WW 48
#define HWSZ (HH*WW)        /* 2304 */
#define NHW (BB*HWSZ)       /* 4608 */
#define TOT (BB*CC*HWSZ)    /* 1179648 */
#define NBG (BB*GG)         /* 16 */
#define KSPLIT 4
#define KSEG (HWSZ/KSPLIT)  /* 576 keys per split = 9 tiles */
#define VTILE 2048          /* shorts per V^T tile: 32 d x 64 keys */
#define NQT 36              /* 64-query tiles */
/* 1/sqrt(32) * log2(e): Q pre-scale so softmax runs in exp2 domain */
#define ATTN_SCALE (0.17677669529663687f * 1.4426950408889634f)

__device__ __align__(16) short g_q[NBG*HWSZ*DD];          // [bg][n][d] bf16, pre-scaled
__device__ __align__(16) short g_k[NBG*HWSZ*DD + 2048];   // [bg][n][d] bf16 (+pad: tail prefetch)
__device__ __align__(16) short g_v[NBG*DD*HWSZ + 2048];   // [bg][tile][d][64key] bf16 (+pad)
__device__ __align__(16) float g_o[TOT];                  // [bg][d][n] fp32 (= channel-major)
__device__ __align__(16) float g_bsum[NBG*NQT*32];        // per-block BN partial sums
__device__ __align__(16) float g_bss[NBG*NQT*32];         // per-block BN partial sumsq

typedef __attribute__((ext_vector_type(8))) short bf16x8;
typedef __attribute__((ext_vector_type(4))) short s16x4;
typedef __attribute__((ext_vector_type(4))) float f32x4;

__device__ __forceinline__ short f2bf(float f) {
    union { float f; unsigned u; } uf; uf.f = f;
    unsigned r = uf.u + 0x7fff + ((uf.u >> 16) & 1);  // RNE
    return (short)(r >> 16);
}
__device__ __forceinline__ unsigned cvt_pk_bf16(float lo, float hi) {
    unsigned w;
    asm("v_cvt_pk_bf16_f32 %0, %1, %2" : "=v"(w) : "v"(lo), "v"(hi));
    return w;
}
#if __has_builtin(__builtin_amdgcn_exp2f)
#define EXP2F(x) __builtin_amdgcn_exp2f(x)
#else
#define EXP2F(x) exp2f(x)
#endif

// ---------------- conv via implicit-GEMM MFMA: 576 blocks x 64 positions ----------------
// Per-block LDS weight packing (pack_w kernel folded in); 4-row halo window.
__global__ __launch_bounds__(256) void conv_mfma(
    const float* __restrict__ x,
    const float* __restrict__ Wq, const float* __restrict__ bq,
    const float* __restrict__ Wk, const float* __restrict__ bk,
    const float* __restrict__ Wv, const float* __restrict__ bv)
{
    __shared__ __align__(16) short xt[4*48*40];        // [rc][ci] pad 40, 30.7 KB
    __shared__ __align__(16) short wq_lds[9*2*16*32];  // [tap][mh][l15][ci], 18 KB
    __shared__ __align__(16) short wk_lds[32*32];      // [c'][ci], 2 KB
    __shared__ __align__(16) short wv_lds[32*32];      // [c'][ci], 2 KB

    int tid = threadIdx.x;
    int bg = blockIdx.x & 15;
    int pt = blockIdx.x >> 4;                // 0..35
    int p0 = pt * 64;
    int b = bg >> 3, g = bg & 7;
    int r0 = p0 / 48 - 1;                    // 4 staged rows r0..r0+3
    const float* xb = x + ((size_t)(b*CC + g*DD)) * HWSZ;

    // stage weights for this group into LDS (pack_w semantics, one block's worth)
    const float* wqg = Wq + (size_t)(g*32) * 288;   // [c'][ci][tap]
    for (int j = tid; j < 9216; j += 256) {
        int c2 = j / 288, rem = j % 288;
        int ci = rem / 9, tap = rem % 9;
        int mh = c2 >> 4, l = c2 & 15;
        wq_lds[((tap*2 + mh)*16 + l)*32 + ci] = f2bf(wqg[(size_t)c2*288 + rem]);
    }
    for (int j = tid; j < 1024; j += 256) {
        wk_lds[j] = f2bf(Wk[(size_t)(g*32)*32 + j]);
        wv_lds[j] = f2bf(Wv[(size_t)(g*32)*32 + j]);
    }

    // stage x rows
    #pragma unroll 4
    for (int i = 0; i < 24; ++i) {
        int cell = tid + i * 256;            // 6144 = 32ci * 192rc
        int ci = cell / 192;
        int rc = cell % 192;
        int row = r0 + rc / 48, col = rc % 48;
        float v = (row >= 0 && row < 48) ? xb[(size_t)ci*HWSZ + row*48 + col] : 0.f;
        xt[rc*40 + ci] = f2bf(v);
    }
    __syncthreads();

    int lane = tid & 63, wave = tid >> 6;
    int l15 = lane & 15, lg = lane >> 4;

    bf16x8 aq[9][2], ak[2], av[2];
    #pragma unroll
    for (int tap = 0; tap < 9; ++tap)
        #pragma unroll
        for (int mh = 0; mh < 2; ++mh)
            aq[tap][mh] = *(const bf16x8*)&wq_lds[((tap*2 + mh)*16 + l15)*32 + lg*8];
    #pragma unroll
    for (int mh = 0; mh < 2; ++mh) {
        ak[mh] = *(const bf16x8*)&wk_lds[(mh*16 + l15)*32 + lg*8];
        av[mh] = *(const bf16x8*)&wv_lds[(mh*16 + l15)*32 + lg*8];
    }
    float bqv[2][4], bkv[2][4], bvv[2][4];
    #pragma unroll
    for (int mh = 0; mh < 2; ++mh)
        #pragma unroll
        for (int j = 0; j < 4; ++j) {
            int c = g*32 + mh*16 + lg*4 + j;
            bqv[mh][j] = bq[c]; bkv[mh][j] = bk[c]; bvv[mh][j] = bv[c];
        }

    size_t qkb = (size_t)bg * HWSZ * DD;
    size_t vb  = (size_t)bg * DD * HWSZ;
    const f32x4 zero = {0.f,0.f,0.f,0.f};

    int n = p0 + wave * 16 + l15;
    int y = n / 48, xcol = n % 48;
    int cell = (y - r0) * 48 + xcol;
    f32x4 cq0 = zero, cq1 = zero, ck0 = zero, ck1 = zero, cv0 = zero, cv1 = zero;
    #pragma unroll
    for (int tap = 0; tap < 9; ++tap) {
        int dy = tap / 3 - 1, dx = tap % 3 - 1;
        int xc = xcol + dx;
        bool ok = (unsigned)xc < 48u;
        int idx = ok ? (cell + dy*48 + dx)*40 + lg*8 : lg*8;
        bf16x8 bx = *(const bf16x8*)&xt[idx];
        if (!ok) bx = bf16x8{0,0,0,0,0,0,0,0};
        cq0 = __builtin_amdgcn_mfma_f32_16x16x32_bf16(aq[tap][0], bx, cq0, 0, 0, 0);
        cq1 = __builtin_amdgcn_mfma_f32_16x16x32_bf16(aq[tap][1], bx, cq1, 0, 0, 0);
        if (tap == 4) {
            ck0 = __builtin_amdgcn_mfma_f32_16x16x32_bf16(ak[0], bx, ck0, 0, 0, 0);
            ck1 = __builtin_amdgcn_mfma_f32_16x16x32_bf16(ak[1], bx, ck1, 0, 0, 0);
            cv0 = __builtin_amdgcn_mfma_f32_16x16x32_bf16(av[0], bx, cv0, 0, 0, 0);
            cv1 = __builtin_amdgcn_mfma_f32_16x16x32_bf16(av[1], bx, cv1, 0, 0, 0);
        }
    }
    int tile = n >> 6, key = n & 63;
    #pragma unroll
    for (int mh = 0; mh < 2; ++mh) {
        f32x4 aQ = mh ? cq1 : cq0;
        f32x4 aK = mh ? ck1 : ck0;
        f32x4 aV = mh ? cv1 : cv0;
        s16x4 pq, pk;
        #pragma unroll
        for (int j = 0; j < 4; ++j) {
            pq[j] = f2bf((aQ[j] + bqv[mh][j]) * ATTN_SCALE);
            pk[j] = f2bf(aK[j] + bkv[mh][j]);
        }
        *(s16x4*)&g_q[qkb + (size_t)n*32 + mh*16 + lg*4] = pq;
        *(s16x4*)&g_k[qkb + (size_t)n*32 + mh*16 + lg*4] = pk;
        #pragma unroll
        for (int j = 0; j < 4; ++j)
            g_v[vb + (size_t)tile*VTILE + (mh*16 + lg*4 + j)*64 + key]
                = f2bf(aV[j] + bvv[mh][j]);
    }
}

// ---------------- attention: 64q/wave (unbounded VGPR), key-split, BN partials ----------------
// block = 256 thr = 4 waves (= 4 ks segments); grid 576.
__global__ __launch_bounds__(256) void attn_mfma()
{
    __shared__ float cmb[KSPLIT][64][34];   // [ks][q][d], 34.8 KB
    __shared__ float cmbl[KSPLIT][64];
    __shared__ float pW[4][32], pWs[4][32]; // per-wave BN partials

    int tid  = threadIdx.x;
    int lane = tid & 63;
    int ks   = tid >> 6;             // wave = key-split segment
    int l15 = lane & 15;
    int lg  = lane >> 4;
    int bg = blockIdx.x & 15;        // XCD clustering: bg, bg+8 per XCD
    int qt = blockIdx.x >> 4;        // 0..35 (64-query tiles)

    const short* qg = g_q + (size_t)bg * HWSZ * DD;
    const short* kg = g_k + (size_t)bg * HWSZ * DD;
    const short* vg = g_v + (size_t)bg * DD * HWSZ;
    int k0 = ks * KSEG;

    bf16x8 aq0 = *(const bf16x8*)&qg[(size_t)(qt*64 + l15)*32 + lg*8];
    bf16x8 aq1 = *(const bf16x8*)&qg[(size_t)(qt*64 + 16 + l15)*32 + lg*8];
    bf16x8 aq2 = *(const bf16x8*)&qg[(size_t)(qt*64 + 32 + l15)*32 + lg*8];
    bf16x8 aq3 = *(const bf16x8*)&qg[(size_t)(qt*64 + 48 + l15)*32 + lg*8];

    f32x4 oc00 = {0.f,0.f,0.f,0.f}, oc01 = {0.f,0.f,0.f,0.f};
    f32x4 oc10 = {0.f,0.f,0.f,0.f}, oc11 = {0.f,0.f,0.f,0.f};
    f32x4 oc20 = {0.f,0.f,0.f,0.f}, oc21 = {0.f,0.f,0.f,0.f};
    f32x4 oc30 = {0.f,0.f,0.f,0.f}, oc31 = {0.f,0.f,0.f,0.f};
    const f32x4 zero = {0.f,0.f,0.f,0.f};
    float lsum0 = 0.f, lsum1 = 0.f, lsum2 = 0.f, lsum3 = 0.f;

    int koff = l15*32 + lg*8;        // + kb*512 (imm) = K frag offset
    int voff = l15*64 + lg*8;        // + w*1024 + h*32 (imm) = V frag offset

    const short* kp = kg + (size_t)k0 * 32;          // current K tile
    const short* vp = vg + (size_t)(ks*9) * VTILE;   // current V tile

    bf16x8 ck[4], cv[4];
    #pragma unroll
    for (int kb = 0; kb < 4; ++kb)
        ck[kb] = *(const bf16x8*)&kp[koff + kb*512];
    #pragma unroll
    for (int h = 0; h < 2; ++h)
        #pragma unroll
        for (int w = 0; w < 2; ++w)
            cv[h*2+w] = *(const bf16x8*)&vp[voff + w*1024 + h*32];

    const short* kq = kp + 2048;     // prefetch pointers (march by one tile)
    const short* vq = vp + VTILE;

    for (int t = 0; t < KSEG/64; ++t) {
        // unconditional prefetch; final iteration reads the pad region (discarded)
        bf16x8 nk[4], nv[4];
        #pragma unroll
        for (int kb = 0; kb < 4; ++kb)
            nk[kb] = *(const bf16x8*)&kq[koff + kb*512];
        #pragma unroll
        for (int h = 0; h < 2; ++h)
            #pragma unroll
            for (int w = 0; w < 2; ++w)
                nv[h*2+w] = *(const bf16x8*)&vq[voff + w*1024 + h*32];

        #pragma unroll
        for (int qf = 0; qf < 4; ++qf) {
            bf16x8 aq = qf == 0 ? aq0 : (qf == 1 ? aq1 : (qf == 2 ? aq2 : aq3));
            f32x4 s[4];
            #pragma unroll
            for (int kb = 0; kb < 4; ++kb)
                s[kb] = __builtin_amdgcn_mfma_f32_16x16x32_bf16(ck[kb], aq, zero, 0, 0, 0);
            unsigned W[4][2];
            float ls = 0.f;
            #pragma unroll
            for (int kb = 0; kb < 4; ++kb) {
                float p0 = EXP2F(s[kb][0]), p1 = EXP2F(s[kb][1]);
                float p2 = EXP2F(s[kb][2]), p3 = EXP2F(s[kb][3]);
                ls += (p0 + p1) + (p2 + p3);
                W[kb][0] = cvt_pk_bf16(p0, p1);
                W[kb][1] = cvt_pk_bf16(p2, p3);
            }
            if (qf == 0) lsum0 += ls; else if (qf == 1) lsum1 += ls;
            else if (qf == 2) lsum2 += ls; else lsum3 += ls;
            #pragma unroll
            for (int h = 0; h < 2; ++h) {
                unsigned a0 = W[2*h][0], b0 = W[2*h+1][0];
                asm("v_permlane32_swap_b32 %0, %1" : "+v"(a0), "+v"(b0));
                asm("v_permlane16_swap_b32 %0, %1" : "+v"(a0), "+v"(b0));
                unsigned a1 = W[2*h][1], b1 = W[2*h+1][1];
                asm("v_permlane32_swap_b32 %0, %1" : "+v"(a1), "+v"(b1));
                asm("v_permlane16_swap_b32 %0, %1" : "+v"(a1), "+v"(b1));
                union { unsigned u[4]; bf16x8 v; } fr;
                fr.u[0] = a0; fr.u[1] = a1; fr.u[2] = b0; fr.u[3] = b1;
                if (qf == 0) {
                    oc00 = __builtin_amdgcn_mfma_f32_16x16x32_bf16(cv[h*2+0], fr.v, oc00, 0, 0, 0);
                    oc01 = __builtin_amdgcn_mfma_f32_16x16x32_bf16(cv[h*2+1], fr.v, oc01, 0, 0, 0);
                } else if (qf == 1) {
                    oc10 = __builtin_amdgcn_mfma_f32_16x16x32_bf16(cv[h*2+0], fr.v, oc10, 0, 0, 0);
                    oc11 = __builtin_amdgcn_mfma_f32_16x16x32_bf16(cv[h*2+1], fr.v, oc11, 0, 0, 0);
                } else if (qf == 2) {
                    oc20 = __builtin_amdgcn_mfma_f32_16x16x32_bf16(cv[h*2+0], fr.v, oc20, 0, 0, 0);
                    oc21 = __builtin_amdgcn_mfma_f32_16x16x32_bf16(cv[h*2+1], fr.v, oc21, 0, 0, 0);
                } else {
                    oc30 = __builtin_amdgcn_mfma_f32_16x16x32_bf16(cv[h*2+0], fr.v, oc30, 0, 0, 0);
                    oc31 = __builtin_amdgcn_mfma_f32_16x16x32_bf16(cv[h*2+1], fr.v, oc31, 0, 0, 0);
                }
            }
        }

        #pragma unroll
        for (int kb = 0; kb < 4; ++kb) ck[kb] = nk[kb];
        #pragma unroll
        for (int i = 0; i < 4; ++i) cv[i] = nv[i];
        kq += 2048;
        vq += VTILE;
    }

    // per-wave denominators (across lg groups; q = l15 column)
    lsum0 += __shfl_xor(lsum0, 16, 64);
    lsum0 += __shfl_xor(lsum0, 32, 64);
    lsum1 += __shfl_xor(lsum1, 16, 64);
    lsum1 += __shfl_xor(lsum1, 32, 64);
    lsum2 += __shfl_xor(lsum2, 16, 64);
    lsum2 += __shfl_xor(lsum2, 32, 64);
    lsum3 += __shfl_xor(lsum3, 16, 64);
    lsum3 += __shfl_xor(lsum3, 32, 64);

    // deposit this wave's partials in LDS
    #pragma unroll
    for (int qf = 0; qf < 4; ++qf) {
        f32x4 a = qf == 0 ? oc00 : (qf == 1 ? oc10 : (qf == 2 ? oc20 : oc30));
        f32x4 b = qf == 0 ? oc01 : (qf == 1 ? oc11 : (qf == 2 ? oc21 : oc31));
        #pragma unroll
        for (int j = 0; j < 4; ++j) {
            cmb[ks][qf*16 + l15][lg*4 + j]      = a[j];
            cmb[ks][qf*16 + l15][16 + lg*4 + j] = b[j];
        }
    }
    if (lg == 0) {
        cmbl[ks][l15]      = lsum0;
        cmbl[ks][16 + l15] = lsum1;
        cmbl[ks][32 + l15] = lsum2;
        cmbl[ks][48 + l15] = lsum3;
    }
    __syncthreads();

    // combine + normalize + store final O (coalesced along n); stash v in cmb[0]
    size_t ob = (size_t)bg * DD * HWSZ;
    int n0 = qt * 64;
    for (int i = tid; i < 64*DD; i += 256) {
        int q = i % 64, d = i / 64;
        float num = cmb[0][q][d] + cmb[1][q][d] + cmb[2][q][d] + cmb[3][q][d];
        float den = cmbl[0][q] + cmbl[1][q] + cmbl[2][q] + cmbl[3][q];
        float v = num / den;
        g_o[ob + (size_t)d * HWSZ + n0 + q] = v;
        cmb[0][q][d] = v;            // same-thread location: safe
    }
    __syncthreads();

    // BN partials: d = tid&31 constant per thread (256 = 0 mod 32) -> no contention
    {
        float s = 0.f, ss = 0.f;
        for (int i = tid; i < 64*DD; i += 256) {
            int d = i & 31, q = i >> 5;
            float v = cmb[0][q][d];
            s += v;
            ss += v * v;
        }
        s  += __shfl_xor(s, 32, 64);   // two lanes per wave share d
        ss += __shfl_xor(ss, 32, 64);
        int wv = tid >> 6;
        if (lane < 32) { pW[wv][lane] = s; pWs[wv][lane] = ss; }
        __syncthreads();
        if (tid < 32) {
            int base = (bg * NQT + qt) * 32 + tid;
            g_bsum[base] = pW[0][tid] + pW[1][tid] + pW[2][tid] + pW[3][tid];
            g_bss[base]  = pWs[0][tid] + pWs[1][tid] + pWs[2][tid] + pWs[3][tid];
        }
    }
}

// ---------------- BN (batch stats from partials) + affine + ReLU: single pass ----------------
__global__ __launch_bounds__(256) void bn_relu(
    const float* __restrict__ gamma, const float* __restrict__ beta,
    float* __restrict__ out)
{
    __shared__ float rs[4], rss[4];
    __shared__ float smean, sinv;
    int c = blockIdx.x;
    int tid = threadIdx.x;
    int g = c >> 5, d = c & 31;

    // phase 1: reduce 72 per-block partials (bg = g and 8+g, qt 0..35)
    float s = 0.f, ss = 0.f;
    for (int i = tid; i < 2*NQT; i += 256) {
        int bgx = (i < NQT) ? g : 8 + g;
        int qq  = (i < NQT) ? i : i - NQT;
        int idx = (bgx * NQT + qq) * 32 + d;
        s  += g_bsum[idx];
        ss += g_bss[idx];
    }
    #pragma unroll
    for (int off = 32; off; off >>= 1) {
        s  += __shfl_down(s, off, 64);
        ss += __shfl_down(ss, off, 64);
    }
    int wid = tid >> 6, lane = tid & 63;
    if (lane == 0) { rs[wid] = s; rss[wid] = ss; }
    __syncthreads();
    if (tid == 0) {
        float ts  = rs[0] + rs[1] + rs[2] + rs[3];
        float tss = rss[0] + rss[1] + rss[2] + rss[3];
        float mean = ts / (float)NHW;
        float var  = tss / (float)NHW - mean * mean;
        smean = mean;
        sinv  = rsqrtf(var + 1e-5f);
    }
    __syncthreads();
    float mean = smean, inv = sinv;
    float ga = gamma[c], be = beta[c];
    const float* o0 = g_o + (size_t)c * HWSZ;
    const float* o1 = g_o + (size_t)(CC + c) * HWSZ;
    float* out0 = out + (size_t)c * HWSZ;
    float* out1 = out + (size_t)(CC + c) * HWSZ;
    for (int i = tid; i < HWSZ; i += 256) {
        float v0 = (o0[i] - mean) * inv * ga + be;
        float v1 = (o1[i] - mean) * inv * ga + be;
        out0[i] = fmaxf(v0, 0.f);
        out1[i] = fmaxf(v1, 0.f);
    }
}

extern "C" void kernel_launch(void* const* d_in, const int* in_sizes, int n_in,
                              void* d_out, int out_size, void* d_ws, size_t ws_size,
                              hipStream_t stream)
{
    const float* x     = (const float*)d_in[0];
    const float* Wq    = (const float*)d_in[1];
    const float* bq    = (const float*)d_in[2];
    const float* Wk    = (const float*)d_in[3];
    const float* bk    = (const float*)d_in[4];
    const float* Wv    = (const float*)d_in[5];
    const float* bv    = (const float*)d_in[6];
    const float* gamma = (const float*)d_in[7];
    const float* beta  = (const float*)d_in[8];
    float* out = (float*)d_out;

    conv_mfma<<<NBG * 36, 256, 0, stream>>>(x, Wq, bq, Wk, bk, Wv, bv);
    attn_mfma<<<NBG * NQT, 256, 0, stream>>>();
    bn_relu<<<CC, 256, 0, stream>>>(gamma, beta, out);
}

// Round 23
// 52.076 us; speedup vs baseline: 1.0230x; 1.0230x over previous
//
#include <hip/hip_runtime.h>
#include <math.h>

#define BB 2
#define CC 256
#define GG 8
#define DD 32
#define HH 48
#define WW 48
#define HWSZ (HH*WW)        /* 2304 */
#define NHW (BB*HWSZ)       /* 4608 */
#define TOT (BB*CC*HWSZ)    /* 1179648 */
#define NBG (BB*GG)         /* 16 */
#define KSPLIT 4
#define KSEG (HWSZ/KSPLIT)  /* 576 keys per split = 9 tiles */
#define VTILE 2048          /* shorts per V^T tile: 32 d x 64 keys */
#define NQT 36              /* 64-query tiles */
/* 1/sqrt(32) * log2(e): Q pre-scale so softmax runs in exp2 domain */
#define ATTN_SCALE (0.17677669529663687f * 1.4426950408889634f)

__device__ __align__(16) short g_q[NBG*HWSZ*DD];          // [bg][n][d] bf16, pre-scaled
__device__ __align__(16) short g_k[NBG*HWSZ*DD + 2048];   // [bg][n][d] bf16 (+pad: tail prefetch)
__device__ __align__(16) short g_v[NBG*DD*HWSZ + 2048];   // [bg][tile][d][64key] bf16 (+pad)
__device__ __align__(16) float g_o[TOT];                  // [bg][d][n] fp32 (= channel-major)
__device__ __align__(16) float g_bsum[NBG*NQT*32];        // per-block BN partial sums
__device__ __align__(16) float g_bss[NBG*NQT*32];         // per-block BN partial sumsq

typedef __attribute__((ext_vector_type(8))) short bf16x8;
typedef __attribute__((ext_vector_type(4))) short s16x4;
typedef __attribute__((ext_vector_type(4))) float f32x4;

__device__ __forceinline__ short f2bf(float f) {
    union { float f; unsigned u; } uf; uf.f = f;
    unsigned r = uf.u + 0x7fff + ((uf.u >> 16) & 1);  // RNE
    return (short)(r >> 16);
}
__device__ __forceinline__ unsigned cvt_pk_bf16(float lo, float hi) {
    unsigned w;
    asm("v_cvt_pk_bf16_f32 %0, %1, %2" : "=v"(w) : "v"(lo), "v"(hi));
    return w;
}
#if __has_builtin(__builtin_amdgcn_exp2f)
#define EXP2F(x) __builtin_amdgcn_exp2f(x)
#else
#define EXP2F(x) exp2f(x)
#endif

// ---------------- conv via implicit-GEMM MFMA: 576 blocks x 64 positions ----------------
// Per-block LDS weight packing; 4-row halo window.
__global__ __launch_bounds__(256) void conv_mfma(
    const float* __restrict__ x,
    const float* __restrict__ Wq, const float* __restrict__ bq,
    const float* __restrict__ Wk, const float* __restrict__ bk,
    const float* __restrict__ Wv, const float* __restrict__ bv)
{
    __shared__ __align__(16) short xt[4*48*40];        // [rc][ci] pad 40
    __shared__ __align__(16) short wq_lds[9*2*16*32];  // [tap][mh][l15][ci], 18 KB
    __shared__ __align__(16) short wk_lds[32*32];      // [c'][ci], 2 KB
    __shared__ __align__(16) short wv_lds[32*32];      // [c'][ci], 2 KB

    int tid = threadIdx.x;
    int bg = blockIdx.x & 15;
    int pt = blockIdx.x >> 4;                // 0..35
    int p0 = pt * 64;
    int b = bg >> 3, g = bg & 7;
    int r0 = p0 / 48 - 1;                    // 4 staged rows r0..r0+3
    const float* xb = x + ((size_t)(b*CC + g*DD)) * HWSZ;

    // stage weights for this group into LDS
    const float* wqg = Wq + (size_t)(g*32) * 288;   // [c'][ci][tap]
    for (int j = tid; j < 9216; j += 256) {
        int c2 = j / 288, rem = j % 288;
        int ci = rem / 9, tap = rem % 9;
        int mh = c2 >> 4, l = c2 & 15;
        wq_lds[((tap*2 + mh)*16 + l)*32 + ci] = f2bf(wqg[(size_t)c2*288 + rem]);
    }
    for (int j = tid; j < 1024; j += 256) {
        wk_lds[j] = f2bf(Wk[(size_t)(g*32)*32 + j]);
        wv_lds[j] = f2bf(Wv[(size_t)(g*32)*32 + j]);
    }

    // stage x rows
    #pragma unroll 4
    for (int i = 0; i < 24; ++i) {
        int cell = tid + i * 256;            // 6144 = 32ci * 192rc
        int ci = cell / 192;
        int rc = cell % 192;
        int row = r0 + rc / 48, col = rc % 48;
        float v = (row >= 0 && row < 48) ? xb[(size_t)ci*HWSZ + row*48 + col] : 0.f;
        xt[rc*40 + ci] = f2bf(v);
    }
    __syncthreads();

    int lane = tid & 63, wave = tid >> 6;
    int l15 = lane & 15, lg = lane >> 4;

    bf16x8 aq[9][2], ak[2], av[2];
    #pragma unroll
    for (int tap = 0; tap < 9; ++tap)
        #pragma unroll
        for (int mh = 0; mh < 2; ++mh)
            aq[tap][mh] = *(const bf16x8*)&wq_lds[((tap*2 + mh)*16 + l15)*32 + lg*8];
    #pragma unroll
    for (int mh = 0; mh < 2; ++mh) {
        ak[mh] = *(const bf16x8*)&wk_lds[(mh*16 + l15)*32 + lg*8];
        av[mh] = *(const bf16x8*)&wv_lds[(mh*16 + l15)*32 + lg*8];
    }
    float bqv[2][4], bkv[2][4], bvv[2][4];
    #pragma unroll
    for (int mh = 0; mh < 2; ++mh)
        #pragma unroll
        for (int j = 0; j < 4; ++j) {
            int c = g*32 + mh*16 + lg*4 + j;
            bqv[mh][j] = bq[c]; bkv[mh][j] = bk[c]; bvv[mh][j] = bv[c];
        }

    size_t qkb = (size_t)bg * HWSZ * DD;
    size_t vb  = (size_t)bg * DD * HWSZ;
    const f32x4 zero = {0.f,0.f,0.f,0.f};

    int n = p0 + wave * 16 + l15;
    int y = n / 48, xcol = n % 48;
    int cell = (y - r0) * 48 + xcol;
    f32x4 cq0 = zero, cq1 = zero, ck0 = zero, ck1 = zero, cv0 = zero, cv1 = zero;
    #pragma unroll
    for (int tap = 0; tap < 9; ++tap) {
        int dy = tap / 3 - 1, dx = tap % 3 - 1;
        int xc = xcol + dx;
        bool ok = (unsigned)xc < 48u;
        int idx = ok ? (cell + dy*48 + dx)*40 + lg*8 : lg*8;
        bf16x8 bx = *(const bf16x8*)&xt[idx];
        if (!ok) bx = bf16x8{0,0,0,0,0,0,0,0};
        cq0 = __builtin_amdgcn_mfma_f32_16x16x32_bf16(aq[tap][0], bx, cq0, 0, 0, 0);
        cq1 = __builtin_amdgcn_mfma_f32_16x16x32_bf16(aq[tap][1], bx, cq1, 0, 0, 0);
        if (tap == 4) {
            ck0 = __builtin_amdgcn_mfma_f32_16x16x32_bf16(ak[0], bx, ck0, 0, 0, 0);
            ck1 = __builtin_amdgcn_mfma_f32_16x16x32_bf16(ak[1], bx, ck1, 0, 0, 0);
            cv0 = __builtin_amdgcn_mfma_f32_16x16x32_bf16(av[0], bx, cv0, 0, 0, 0);
            cv1 = __builtin_amdgcn_mfma_f32_16x16x32_bf16(av[1], bx, cv1, 0, 0, 0);
        }
    }
    int tile = n >> 6, key = n & 63;
    #pragma unroll
    for (int mh = 0; mh < 2; ++mh) {
        f32x4 aQ = mh ? cq1 : cq0;
        f32x4 aK = mh ? ck1 : ck0;
        f32x4 aV = mh ? cv1 : cv0;
        s16x4 pq, pk;
        #pragma unroll
        for (int j = 0; j < 4; ++j) {
            pq[j] = f2bf((aQ[j] + bqv[mh][j]) * ATTN_SCALE);
            pk[j] = f2bf(aK[j] + bkv[mh][j]);
        }
        *(s16x4*)&g_q[qkb + (size_t)n*32 + mh*16 + lg*4] = pq;
        *(s16x4*)&g_k[qkb + (size_t)n*32 + mh*16 + lg*4] = pk;
        #pragma unroll
        for (int j = 0; j < 4; ++j)
            g_v[vb + (size_t)tile*VTILE + (mh*16 + lg*4 + j)*64 + key]
                = f2bf(aV[j] + bvv[mh][j]);
    }
}

// ---------------- attention: 64q/wave, key-split, BN partials (R21-proven) ----------------
__global__ __launch_bounds__(256) void attn_mfma()
{
    __shared__ float cmb[KSPLIT][64][34];   // [ks][q][d], 34.8 KB
    __shared__ float cmbl[KSPLIT][64];
    __shared__ float pW[4][32], pWs[4][32]; // per-wave BN partials

    int tid  = threadIdx.x;
    int lane = tid & 63;
    int ks   = tid >> 6;             // wave = key-split segment
    int l15 = lane & 15;
    int lg  = lane >> 4;
    int bg = blockIdx.x & 15;        // XCD clustering: bg, bg+8 per XCD
    int qt = blockIdx.x >> 4;        // 0..35 (64-query tiles)

    const short* qg = g_q + (size_t)bg * HWSZ * DD;
    const short* kg = g_k + (size_t)bg * HWSZ * DD;
    const short* vg = g_v + (size_t)bg * DD * HWSZ;
    int k0 = ks * KSEG;

    bf16x8 aq0 = *(const bf16x8*)&qg[(size_t)(qt*64 + l15)*32 + lg*8];
    bf16x8 aq1 = *(const bf16x8*)&qg[(size_t)(qt*64 + 16 + l15)*32 + lg*8];
    bf16x8 aq2 = *(const bf16x8*)&qg[(size_t)(qt*64 + 32 + l15)*32 + lg*8];
    bf16x8 aq3 = *(const bf16x8*)&qg[(size_t)(qt*64 + 48 + l15)*32 + lg*8];

    f32x4 oc00 = {0.f,0.f,0.f,0.f}, oc01 = {0.f,0.f,0.f,0.f};
    f32x4 oc10 = {0.f,0.f,0.f,0.f}, oc11 = {0.f,0.f,0.f,0.f};
    f32x4 oc20 = {0.f,0.f,0.f,0.f}, oc21 = {0.f,0.f,0.f,0.f};
    f32x4 oc30 = {0.f,0.f,0.f,0.f}, oc31 = {0.f,0.f,0.f,0.f};
    const f32x4 zero = {0.f,0.f,0.f,0.f};
    float lsum0 = 0.f, lsum1 = 0.f, lsum2 = 0.f, lsum3 = 0.f;

    int koff = l15*32 + lg*8;        // + kb*512 (imm) = K frag offset
    int voff = l15*64 + lg*8;        // + w*1024 + h*32 (imm) = V frag offset

    const short* kp = kg + (size_t)k0 * 32;          // current K tile
    const short* vp = vg + (size_t)(ks*9) * VTILE;   // current V tile

    bf16x8 ck[4], cv[4];
    #pragma unroll
    for (int kb = 0; kb < 4; ++kb)
        ck[kb] = *(const bf16x8*)&kp[koff + kb*512];
    #pragma unroll
    for (int h = 0; h < 2; ++h)
        #pragma unroll
        for (int w = 0; w < 2; ++w)
            cv[h*2+w] = *(const bf16x8*)&vp[voff + w*1024 + h*32];

    const short* kq = kp + 2048;     // prefetch pointers (march by one tile)
    const short* vq = vp + VTILE;

    for (int t = 0; t < KSEG/64; ++t) {
        bf16x8 nk[4], nv[4];
        #pragma unroll
        for (int kb = 0; kb < 4; ++kb)
            nk[kb] = *(const bf16x8*)&kq[koff + kb*512];
        #pragma unroll
        for (int h = 0; h < 2; ++h)
            #pragma unroll
            for (int w = 0; w < 2; ++w)
                nv[h*2+w] = *(const bf16x8*)&vq[voff + w*1024 + h*32];

        #pragma unroll
        for (int qf = 0; qf < 4; ++qf) {
            bf16x8 aq = qf == 0 ? aq0 : (qf == 1 ? aq1 : (qf == 2 ? aq2 : aq3));
            f32x4 s[4];
            #pragma unroll
            for (int kb = 0; kb < 4; ++kb)
                s[kb] = __builtin_amdgcn_mfma_f32_16x16x32_bf16(ck[kb], aq, zero, 0, 0, 0);
            unsigned W[4][2];
            float ls = 0.f;
            #pragma unroll
            for (int kb = 0; kb < 4; ++kb) {
                float p0 = EXP2F(s[kb][0]), p1 = EXP2F(s[kb][1]);
                float p2 = EXP2F(s[kb][2]), p3 = EXP2F(s[kb][3]);
                ls += (p0 + p1) + (p2 + p3);
                W[kb][0] = cvt_pk_bf16(p0, p1);
                W[kb][1] = cvt_pk_bf16(p2, p3);
            }
            if (qf == 0) lsum0 += ls; else if (qf == 1) lsum1 += ls;
            else if (qf == 2) lsum2 += ls; else lsum3 += ls;
            #pragma unroll
            for (int h = 0; h < 2; ++h) {
                unsigned a0 = W[2*h][0], b0 = W[2*h+1][0];
                asm("v_permlane32_swap_b32 %0, %1" : "+v"(a0), "+v"(b0));
                asm("v_permlane16_swap_b32 %0, %1" : "+v"(a0), "+v"(b0));
                unsigned a1 = W[2*h][1], b1 = W[2*h+1][1];
                asm("v_permlane32_swap_b32 %0, %1" : "+v"(a1), "+v"(b1));
                asm("v_permlane16_swap_b32 %0, %1" : "+v"(a1), "+v"(b1));
                union { unsigned u[4]; bf16x8 v; } fr;
                fr.u[0] = a0; fr.u[1] = a1; fr.u[2] = b0; fr.u[3] = b1;
                if (qf == 0) {
                    oc00 = __builtin_amdgcn_mfma_f32_16x16x32_bf16(cv[h*2+0], fr.v, oc00, 0, 0, 0);
                    oc01 = __builtin_amdgcn_mfma_f32_16x16x32_bf16(cv[h*2+1], fr.v, oc01, 0, 0, 0);
                } else if (qf == 1) {
                    oc10 = __builtin_amdgcn_mfma_f32_16x16x32_bf16(cv[h*2+0], fr.v, oc10, 0, 0, 0);
                    oc11 = __builtin_amdgcn_mfma_f32_16x16x32_bf16(cv[h*2+1], fr.v, oc11, 0, 0, 0);
                } else if (qf == 2) {
                    oc20 = __builtin_amdgcn_mfma_f32_16x16x32_bf16(cv[h*2+0], fr.v, oc20, 0, 0, 0);
                    oc21 = __builtin_amdgcn_mfma_f32_16x16x32_bf16(cv[h*2+1], fr.v, oc21, 0, 0, 0);
                } else {
                    oc30 = __builtin_amdgcn_mfma_f32_16x16x32_bf16(cv[h*2+0], fr.v, oc30, 0, 0, 0);
                    oc31 = __builtin_amdgcn_mfma_f32_16x16x32_bf16(cv[h*2+1], fr.v, oc31, 0, 0, 0);
                }
            }
        }

        #pragma unroll
        for (int kb = 0; kb < 4; ++kb) ck[kb] = nk[kb];
        #pragma unroll
        for (int i = 0; i < 4; ++i) cv[i] = nv[i];
        kq += 2048;
        vq += VTILE;
    }

    lsum0 += __shfl_xor(lsum0, 16, 64);
    lsum0 += __shfl_xor(lsum0, 32, 64);
    lsum1 += __shfl_xor(lsum1, 16, 64);
    lsum1 += __shfl_xor(lsum1, 32, 64);
    lsum2 += __shfl_xor(lsum2, 16, 64);
    lsum2 += __shfl_xor(lsum2, 32, 64);
    lsum3 += __shfl_xor(lsum3, 16, 64);
    lsum3 += __shfl_xor(lsum3, 32, 64);

    #pragma unroll
    for (int qf = 0; qf < 4; ++qf) {
        f32x4 a = qf == 0 ? oc00 : (qf == 1 ? oc10 : (qf == 2 ? oc20 : oc30));
        f32x4 b = qf == 0 ? oc01 : (qf == 1 ? oc11 : (qf == 2 ? oc21 : oc31));
        #pragma unroll
        for (int j = 0; j < 4; ++j) {
            cmb[ks][qf*16 + l15][lg*4 + j]      = a[j];
            cmb[ks][qf*16 + l15][16 + lg*4 + j] = b[j];
        }
    }
    if (lg == 0) {
        cmbl[ks][l15]      = lsum0;
        cmbl[ks][16 + l15] = lsum1;
        cmbl[ks][32 + l15] = lsum2;
        cmbl[ks][48 + l15] = lsum3;
    }
    __syncthreads();

    // combine + normalize + store final O (coalesced along n); stash v in cmb[0]
    size_t ob = (size_t)bg * DD * HWSZ;
    int n0 = qt * 64;
    for (int i = tid; i < 64*DD; i += 256) {
        int q = i % 64, d = i / 64;
        float num = cmb[0][q][d] + cmb[1][q][d] + cmb[2][q][d] + cmb[3][q][d];
        float den = cmbl[0][q] + cmbl[1][q] + cmbl[2][q] + cmbl[3][q];
        float v = num / den;
        g_o[ob + (size_t)d * HWSZ + n0 + q] = v;
        cmb[0][q][d] = v;            // same-thread location: safe
    }
    __syncthreads();

    // BN partials: d = tid&31 constant per thread -> no contention
    {
        float s = 0.f, ss = 0.f;
        for (int i = tid; i < 64*DD; i += 256) {
            int d = i & 31, q = i >> 5;
            float v = cmb[0][q][d];
            s += v;
            ss += v * v;
        }
        s  += __shfl_xor(s, 32, 64);
        ss += __shfl_xor(ss, 32, 64);
        int wv = tid >> 6;
        if (lane < 32) { pW[wv][lane] = s; pWs[wv][lane] = ss; }
        __syncthreads();
        if (tid < 32) {
            int base = (bg * NQT + qt) * 32 + tid;
            g_bsum[base] = pW[0][tid] + pW[1][tid] + pW[2][tid] + pW[3][tid];
            g_bss[base]  = pWs[0][tid] + pWs[1][tid] + pWs[2][tid] + pWs[3][tid];
        }
    }
}

// ---------------- BN (stats from partials) + affine + ReLU: 512 blocks ----------------
__global__ __launch_bounds__(256) void bn_relu(
    const float* __restrict__ gamma, const float* __restrict__ beta,
    float* __restrict__ out)
{
    __shared__ float rs[4], rss[4];
    __shared__ float smean, sinv;
    int c    = blockIdx.x >> 1;
    int half = blockIdx.x & 1;
    int tid = threadIdx.x;
    int g = c >> 5, d = c & 31;

    // phase 1: reduce 72 per-block partials (redundant across the 2 halves; cheap)
    float s = 0.f, ss = 0.f;
    for (int i = tid; i < 2*NQT; i += 256) {
        int bgx = (i < NQT) ? g : 8 + g;
        int qq  = (i < NQT) ? i : i - NQT;
        int idx = (bgx * NQT + qq) * 32 + d;
        s  += g_bsum[idx];
        ss += g_bss[idx];
    }
    #pragma unroll
    for (int off = 32; off; off >>= 1) {
        s  += __shfl_down(s, off, 64);
        ss += __shfl_down(ss, off, 64);
    }
    int wid = tid >> 6, lane = tid & 63;
    if (lane == 0) { rs[wid] = s; rss[wid] = ss; }
    __syncthreads();
    if (tid == 0) {
        float ts  = rs[0] + rs[1] + rs[2] + rs[3];
        float tss = rss[0] + rss[1] + rss[2] + rss[3];
        float mean = ts / (float)NHW;
        float var  = tss / (float)NHW - mean * mean;
        smean = mean;
        sinv  = rsqrtf(var + 1e-5f);
    }
    __syncthreads();
    float mean = smean, inv = sinv;
    float ga = gamma[c], be = beta[c];
    const float* o0 = g_o + (size_t)c * HWSZ;
    const float* o1 = g_o + (size_t)(CC + c) * HWSZ;
    float* out0 = out + (size_t)c * HWSZ;
    float* out1 = out + (size_t)(CC + c) * HWSZ;
    int i0 = half * (HWSZ/2), i1 = i0 + HWSZ/2;
    for (int i = i0 + tid; i < i1; i += 256) {
        float v0 = (o0[i] - mean) * inv * ga + be;
        float v1 = (o1[i] - mean) * inv * ga + be;
        out0[i] = fmaxf(v0, 0.f);
        out1[i] = fmaxf(v1, 0.f);
    }
}

extern "C" void kernel_launch(void* const* d_in, const int* in_sizes, int n_in,
                              void* d_out, int out_size, void* d_ws, size_t ws_size,
                              hipStream_t stream)
{
    const float* x     = (const float*)d_in[0];
    const float* Wq    = (const float*)d_in[1];
    const float* bq    = (const float*)d_in[2];
    const float* Wk    = (const float*)d_in[3];
    const float* bk    = (const float*)d_in[4];
    const float* Wv    = (const float*)d_in[5];
    const float* bv    = (const float*)d_in[6];
    const float* gamma = (const float*)d_in[7];
    const float* beta  = (const float*)d_in[8];
    float* out = (float*)d_out;

    conv_mfma<<<NBG * 36, 256, 0, stream>>>(x, Wq, bq, Wk, bk, Wv, bv);
    attn_mfma<<<NBG * NQT, 256, 0, stream>>>();
    bn_relu<<<CC * 2, 256, 0, stream>>>(gamma, beta, out);
}